// Round 15
// baseline (5215.899 us; speedup 1.0000x reference)
//
#include <hip/hip_runtime.h>
#include <math.h>

#define NC 10
#define KITERS 10
// B=8, S=4096, D=256, K=1024, tokens = 32768
// Bit-exact r10/r13 decision semantics. r14's k_sums had a double-buffer bug:
// sa was overwritten by the prefetch before compute consumed it (chunk c summed
// with chunk c+1's assignments). Fixed with sa_cur/sa_nxt rotation.
// absmax must equal 0.001953125 exactly.

#define SWZ(row, q) ((q) ^ (((row) >> 2) & 15))

// np.sum((x-c)^2) over 256 contiguous: EXACT r10 order.
__device__ __forceinline__ float sumsqdiff256_np(const float* __restrict__ x,
                                                 const float* __restrict__ c) {
  float blk[2];
#pragma unroll
  for (int bI = 0; bI < 2; ++bI) {
    const float* px = x + bI * 128;
    const float* pc = c + bI * 128;
    float r[8];
#pragma unroll
    for (int j = 0; j < 8; ++j) {
      const float d = __fsub_rn(px[j], pc[j]);
      r[j] = __fmul_rn(d, d);
    }
#pragma unroll
    for (int i = 8; i < 128; i += 8)
#pragma unroll
      for (int j = 0; j < 8; ++j) {
        const float d = __fsub_rn(px[i + j], pc[i + j]);
        r[j] = __fadd_rn(r[j], __fmul_rn(d, d));
      }
    blk[bI] = __fadd_rn(__fadd_rn(__fadd_rn(r[0], r[1]), __fadd_rn(r[2], r[3])),
                        __fadd_rn(__fadd_rn(r[4], r[5]), __fadd_rn(r[6], r[7])));
  }
  return __fadd_rn(blk[0], blk[1]);
}

// ---------------- K1: sim + top5 + softmax + x_enh ----------------
// 512 blocks x 256 thr; 64 tokens/block; chunk = 64 mem rows (16 chunks).
// thread (tg = tid>>4, kg = tid&15): tokens 4tg..4tg+3, k-rows 4kg..4kg+3.
// Dot = exact SSE 4-acc chain over q ascending (bit-identical to r10).
extern __shared__ float4 lds4[];  // 8192 float4 = 128 KB (dynamic)
__global__ __launch_bounds__(256, 1) void k_enh(const float* __restrict__ x,
                                                const float* __restrict__ mem,
                                                float* __restrict__ xenh) {
  float4* xt = lds4;          // 64 rows x 64 f4 (64 KB), swizzled
  float4* mt = lds4 + 4096;   // 64 rows x 64 f4 (64 KB), swizzled
  // aliases used AFTER the main loop (x-region dead by then):
  float* cv = (float*)lds4;             // [64][80]
  int*   ck = (int*)lds4 + 5120;        // [64][80]
  float* av = (float*)lds4 + 10240;     // [64][5]
  int*   ak = (int*)lds4 + 10560;       // [64][5]

  const int tid = threadIdx.x;
  const int tg = tid >> 4;
  const int kg = tid & 15;
  const int tokenBase = blockIdx.x * 64;

  {  // stage x (64 KB) + mem chunk 0, swizzled
    const float4* xg = (const float4*)(x + (size_t)tokenBase * 256);
    const float4* mg = (const float4*)mem;
#pragma unroll
    for (int i = 0; i < 16; ++i) {
      const int p = tid + 256 * i;
      const int row = p >> 6, q = p & 63;
      xt[row * 64 + SWZ(row, q)] = xg[p];
      mt[row * 64 + SWZ(row, q)] = mg[p];
    }
  }
  __syncthreads();

  float t5v[4][5]; int t5k[4][5];
#pragma unroll
  for (int i = 0; i < 4; ++i)
#pragma unroll
    for (int r = 0; r < 5; ++r) { t5v[i][r] = -INFINITY; t5k[i][r] = 0; }

  for (int kc = 0; kc < 16; ++kc) {
    float4 st[16];
    if (kc < 15) {  // prefetch next chunk to regs (in flight during compute)
      const float4* mg = (const float4*)mem + (size_t)(kc + 1) * 4096;
#pragma unroll
      for (int i = 0; i < 16; ++i) st[i] = mg[tid + 256 * i];
    }

    float4 acc[4][4];
#pragma unroll
    for (int i = 0; i < 4; ++i)
#pragma unroll
      for (int j = 0; j < 4; ++j) acc[i][j] = make_float4(0.f, 0.f, 0.f, 0.f);

#pragma unroll 4
    for (int q = 0; q < 64; ++q) {
      float4 mv[4], xv[4];
#pragma unroll
      for (int j = 0; j < 4; ++j) {
        const int row = 4 * kg + j;
        mv[j] = mt[row * 64 + SWZ(row, q)];
      }
#pragma unroll
      for (int i = 0; i < 4; ++i) {
        const int row = 4 * tg + i;
        xv[i] = xt[row * 64 + SWZ(row, q)];
      }
#pragma unroll
      for (int i = 0; i < 4; ++i)
#pragma unroll
        for (int j = 0; j < 4; ++j) {
          acc[i][j].x = __fadd_rn(acc[i][j].x, __fmul_rn(xv[i].x, mv[j].x));
          acc[i][j].y = __fadd_rn(acc[i][j].y, __fmul_rn(xv[i].y, mv[j].y));
          acc[i][j].z = __fadd_rn(acc[i][j].z, __fmul_rn(xv[i].z, mv[j].z));
          acc[i][j].w = __fadd_rn(acc[i][j].w, __fmul_rn(xv[i].w, mv[j].w));
        }
    }

    // top-5 insertion: k ascending within step, kc ascending across steps
#pragma unroll
    for (int i = 0; i < 4; ++i)
#pragma unroll
      for (int j = 0; j < 4; ++j) {
        const float v = __fadd_rn(__fadd_rn(acc[i][j].x, acc[i][j].z),
                                  __fadd_rn(acc[i][j].y, acc[i][j].w));
        const int kk = kc * 64 + 4 * kg + j;
        if (v > t5v[i][4]) {
          t5v[i][4] = v; t5k[i][4] = kk;
          if (t5v[i][4] > t5v[i][3]) { float a = t5v[i][3]; t5v[i][3] = t5v[i][4]; t5v[i][4] = a; int ia = t5k[i][3]; t5k[i][3] = t5k[i][4]; t5k[i][4] = ia; }
          if (t5v[i][3] > t5v[i][2]) { float a = t5v[i][2]; t5v[i][2] = t5v[i][3]; t5v[i][3] = a; int ia = t5k[i][2]; t5k[i][2] = t5k[i][3]; t5k[i][3] = ia; }
          if (t5v[i][2] > t5v[i][1]) { float a = t5v[i][1]; t5v[i][1] = t5v[i][2]; t5v[i][2] = a; int ia = t5k[i][1]; t5k[i][1] = t5k[i][2]; t5k[i][2] = ia; }
          if (t5v[i][1] > t5v[i][0]) { float a = t5v[i][0]; t5v[i][0] = t5v[i][1]; t5v[i][1] = a; int ia = t5k[i][0]; t5k[i][0] = t5k[i][1]; t5k[i][1] = ia; }
        }
      }

    __syncthreads();  // all reads of mt done
    if (kc < 15) {
#pragma unroll
      for (int i = 0; i < 16; ++i) {
        const int p = tid + 256 * i;
        const int row = p >> 6, q = p & 63;
        mt[row * 64 + SWZ(row, q)] = st[i];
      }
      __syncthreads();
    }
  }
  __syncthreads();  // x-region now dead -> publish candidates into aliases

#pragma unroll
  for (int i = 0; i < 4; ++i) {
    const int token = 4 * tg + i;
#pragma unroll
    for (int r = 0; r < 5; ++r) {
      cv[token * 80 + kg * 5 + r] = t5v[i][r];
      ck[token * 80 + kg * 5 + r] = t5k[i][r];
    }
  }
  __syncthreads();

  if (tid < 64) {  // merge 80 candidates: value desc, tie -> lower k (stable)
    const int token = tid;
    float tv[5]; int tk[5];
#pragma unroll
    for (int r = 0; r < 5; ++r) {
      float best = -INFINITY; int bi = 0, bk = 0x7fffffff;
      for (int c = 0; c < 80; ++c) {
        const float vv = cv[token * 80 + c]; const int kkc = ck[token * 80 + c];
        if (vv > best || (vv == best && kkc < bk)) { best = vv; bi = c; bk = kkc; }
      }
      tv[r] = best; tk[r] = bk; cv[token * 80 + bi] = -INFINITY;
    }
    float mx = tv[0];
#pragma unroll
    for (int r = 1; r < 5; ++r) mx = fmaxf(mx, tv[r]);
    float e[5];
#pragma unroll
    for (int r = 0; r < 5; ++r)
      e[r] = (float)exp((double)__fsub_rn(tv[r], mx));
    float s = e[0];
#pragma unroll
    for (int r = 1; r < 5; ++r) s = __fadd_rn(s, e[r]);
#pragma unroll
    for (int r = 0; r < 5; ++r) { av[token * 5 + r] = __fdiv_rn(e[r], s); ak[token * 5 + r] = tk[r]; }
  }
  __syncthreads();

  // x_enh epilogue: re-read x from global; chain identical to r10
#pragma unroll
  for (int i = 0; i < 16; ++i) {
    const int flat = tid + 256 * i;          // 0..4095 quads
    const int token = flat >> 6, q = flat & 63;
    const float a0 = av[token * 5 + 0], a1 = av[token * 5 + 1], a2 = av[token * 5 + 2],
                a3 = av[token * 5 + 3], a4 = av[token * 5 + 4];
    const float4 xv = ((const float4*)(x + (size_t)(tokenBase + token) * 256))[q];
    const float4 m0 = ((const float4*)(mem + (size_t)ak[token * 5 + 0] * 256))[q];
    const float4 m1 = ((const float4*)(mem + (size_t)ak[token * 5 + 1] * 256))[q];
    const float4 m2 = ((const float4*)(mem + (size_t)ak[token * 5 + 2] * 256))[q];
    const float4 m3 = ((const float4*)(mem + (size_t)ak[token * 5 + 3] * 256))[q];
    const float4 m4 = ((const float4*)(mem + (size_t)ak[token * 5 + 4] * 256))[q];
    float4 o;
    {
      float ctx = __fmul_rn(a0, m0.x);
      ctx = __fadd_rn(ctx, __fmul_rn(a1, m1.x));
      ctx = __fadd_rn(ctx, __fmul_rn(a2, m2.x));
      ctx = __fadd_rn(ctx, __fmul_rn(a3, m3.x));
      ctx = __fadd_rn(ctx, __fmul_rn(a4, m4.x));
      o.x = __fadd_rn(xv.x, ctx);
    }
    {
      float ctx = __fmul_rn(a0, m0.y);
      ctx = __fadd_rn(ctx, __fmul_rn(a1, m1.y));
      ctx = __fadd_rn(ctx, __fmul_rn(a2, m2.y));
      ctx = __fadd_rn(ctx, __fmul_rn(a3, m3.y));
      ctx = __fadd_rn(ctx, __fmul_rn(a4, m4.y));
      o.y = __fadd_rn(xv.y, ctx);
    }
    {
      float ctx = __fmul_rn(a0, m0.z);
      ctx = __fadd_rn(ctx, __fmul_rn(a1, m1.z));
      ctx = __fadd_rn(ctx, __fmul_rn(a2, m2.z));
      ctx = __fadd_rn(ctx, __fmul_rn(a3, m3.z));
      ctx = __fadd_rn(ctx, __fmul_rn(a4, m4.z));
      o.z = __fadd_rn(xv.z, ctx);
    }
    {
      float ctx = __fmul_rn(a0, m0.w);
      ctx = __fadd_rn(ctx, __fmul_rn(a1, m1.w));
      ctx = __fadd_rn(ctx, __fmul_rn(a2, m2.w));
      ctx = __fadd_rn(ctx, __fmul_rn(a3, m3.w));
      ctx = __fadd_rn(ctx, __fmul_rn(a4, m4.w));
      o.w = __fadd_rn(xv.w, ctx);
    }
    ((float4*)(xenh + (size_t)tokenBase * 256))[flat] = o;
  }
}

// ---------------- zero the per-iteration count buffers ----------------
__global__ __launch_bounds__(256) void k_zero(int* __restrict__ p, int n) {
  const int i = blockIdx.x * 256 + threadIdx.x;
  if (i < n) p[i] = 0;
}

// ---------------- K3: init centroids (bit copy of x_enh rows) ----------------
__global__ __launch_bounds__(64) void k_init(const float* __restrict__ xenh,
                                             const int* __restrict__ init_idx,
                                             float* __restrict__ cent) {
  const int i = blockIdx.x;  // b*10 + j
  const int b = i / NC;
  const int s = init_idx[i];
  const int l = threadIdx.x;
  ((float4*)(cent + (size_t)i * 256))[l] =
      ((const float4*)(xenh + ((size_t)b * 4096 + s) * 256))[l];
}

// ---------------- K5: assignment (LDS-staged rows; exact r10 dist chains) ----------------
__global__ __launch_bounds__(256) void k_assign(const float* __restrict__ xenh,
                                                const float* __restrict__ cent,
                                                int* __restrict__ assign,
                                                int* __restrict__ cnt) {
  __shared__ float xls[32 * 257];   // +1 pad -> conflict-free lane reads
  __shared__ float cl[NC * 256];
  const int tid = threadIdx.x;
  const int tokenBase = blockIdx.x * 32;
  const int b = blockIdx.x >> 7;    // 128 blocks per batch
  for (int i = tid; i < NC * 256; i += 256)
    cl[i] = cent[(size_t)b * NC * 256 + i];
  {
    const float* xg = xenh + (size_t)tokenBase * 256;
#pragma unroll 8
    for (int i = 0; i < 32; ++i) {
      const int e = tid + 256 * i;
      const int row = e >> 8, col = e & 255;
      xls[row * 257 + col] = xg[e];
    }
  }
  __syncthreads();
  if (tid < 32) {
    const float* xrow = xls + tid * 257;
    float best = INFINITY; int bk = 0;
#pragma unroll
    for (int k = 0; k < NC; ++k) {
      const float dist = sumsqdiff256_np(xrow, cl + k * 256);
      if (dist < best) { best = dist; bk = k; }
    }
    assign[tokenBase + tid] = bk;
#pragma unroll
    for (int k = 0; k < NC; ++k) {
      const unsigned long long m = __ballot(bk == k);
      if (tid == 0) atomicAdd(&cnt[b * NC + k], (int)__popcll(m));
    }
  }
}

// ---------------- K6: cluster sums -- block per (b,k); LDS-staged s-chunks ----------------
// Chain strictly s-ascending with (a==k)?xe:+0.0 adds == r10 order (bit-exact).
// sa_cur/sa_nxt rotation (r14 bug: sa overwritten before use).
__global__ __launch_bounds__(256) void k_sums(const float* __restrict__ xenh,
                                              const int* __restrict__ assign,
                                              const int* __restrict__ cnt,
                                              float* __restrict__ cent) {
  __shared__ float sb[2][32 * 256];  // 2 x 32 KB
  const int bid = blockIdx.x;        // 80 = 8b x 10k
  const int b = bid / NC, k = bid % NC;
  const int d = threadIdx.x;
  const float* xb = xenh + (size_t)b * 4096 * 256;
  const int* as = assign + b * 4096;

  float4 st[8]; int sa_cur, sa_nxt;
  {  // prologue: stage chunk 0
    const float4* g0 = (const float4*)xb;
#pragma unroll
    for (int i = 0; i < 8; ++i) st[i] = g0[d + 256 * i];
    sa_cur = as[d & 31];
#pragma unroll
    for (int i = 0; i < 8; ++i) ((float4*)sb[0])[d + 256 * i] = st[i];
  }
  __syncthreads();

  float acc = 0.0f;
  for (int c = 0; c < 128; ++c) {
    if (c < 127) {  // prefetch next chunk to regs (do NOT touch sa_cur)
      const float4* gn = (const float4*)(xb + (size_t)(c + 1) * 32 * 256);
#pragma unroll
      for (int i = 0; i < 8; ++i) st[i] = gn[d + 256 * i];
      sa_nxt = as[(c + 1) * 32 + (d & 31)];
    }
    const float* sc = sb[c & 1];
#pragma unroll
    for (int s = 0; s < 32; ++s) {
      const int a = __shfl(sa_cur, s);  // uniform lane idx -> readlane broadcast
      const float xe = sc[s * 256 + d];
      acc = __fadd_rn(acc, (a == k) ? xe : 0.0f);
    }
    __syncthreads();  // all reads of sb[c&1] done
    if (c < 127) {
#pragma unroll
      for (int i = 0; i < 8; ++i) ((float4*)sb[(c + 1) & 1])[d + 256 * i] = st[i];
      sa_cur = sa_nxt;
      __syncthreads();
    }
  }
  const int cc = cnt[b * NC + k];
  cent[((size_t)(b * NC + k)) * 256 + d] = (cc == 0) ? 0.0f : __fdiv_rn(acc, (float)cc);
}

// ---------------- K7: quantize ----------------
__global__ __launch_bounds__(256) void k_quant(const float* __restrict__ cent,
                                               const int* __restrict__ assign,
                                               float* __restrict__ out) {
  const int token = blockIdx.x * 4 + (threadIdx.x >> 6);
  const int l = threadIdx.x & 63;
  const int b = token >> 12;
  const int a = assign[token];
  ((float4*)out)[(size_t)token * 64 + l] =
      ((const float4*)cent)[(size_t)(b * NC + a) * 64 + l];
}

extern "C" void kernel_launch(void* const* d_in, const int* in_sizes, int n_in,
                              void* d_out, int out_size, void* d_ws, size_t ws_size,
                              hipStream_t stream) {
  const float* x = (const float*)d_in[0];      // [8,4096,256] f32
  const float* mem = (const float*)d_in[1];    // [1024,256] f32
  const int* init_idx = (const int*)d_in[2];   // [8,10] i32
  float* xenh = (float*)d_out;                 // x_enh materialized in d_out
  char* ws = (char*)d_ws;

  float* cent   = (float*)(ws);                //  81920 B
  int*   assign = (int*)  (ws + 81920);        // 131072 B
  int*   cntbuf = (int*)  (ws + 212992);       // KITERS*8*NC ints

  (void)hipFuncSetAttribute((const void*)k_enh,
                            hipFuncAttributeMaxDynamicSharedMemorySize, 131072);

  k_zero<<<4, 256, 0, stream>>>(cntbuf, KITERS * 8 * NC);
  k_enh<<<512, 256, 131072, stream>>>(x, mem, xenh);
  k_init<<<80, 64, 0, stream>>>(xenh, init_idx, cent);
  for (int it = 0; it < KITERS; ++it) {
    k_assign<<<1024, 256, 0, stream>>>(xenh, cent, assign, cntbuf + it * 8 * NC);
    k_sums<<<80, 256, 0, stream>>>(xenh, assign, cntbuf + it * 8 * NC, cent);
  }
  k_quant<<<8192, 256, 0, stream>>>(cent, assign, (float*)d_out);
}

// Round 16
// 2740.431 us; speedup vs baseline: 1.9033x; 1.9033x over previous
//
#include <hip/hip_runtime.h>
#include <math.h>

#define NC 10
#define KITERS 10
// B=8, S=4096, D=256, K=1024, tokens = 32768
// Bit-exact r10 decision semantics. r16: k_assign uses all lanes (2 lanes per
// token, independent 128-block folds + commutative pair-combine); k_sums
// reverted to r13's proven direct-global chain. absmax must equal 0.001953125.

#define SWZ(row, q) ((q) ^ (((row) >> 2) & 15))

// np.sum((x-c)^2) over one 128-block: EXACT r10 per-block order.
__device__ __forceinline__ float sumsqdiff128_np(const float* __restrict__ px,
                                                 const float* __restrict__ pc) {
  float r[8];
#pragma unroll
  for (int j = 0; j < 8; ++j) {
    const float d = __fsub_rn(px[j], pc[j]);
    r[j] = __fmul_rn(d, d);
  }
#pragma unroll
  for (int i = 8; i < 128; i += 8)
#pragma unroll
    for (int j = 0; j < 8; ++j) {
      const float d = __fsub_rn(px[i + j], pc[i + j]);
      r[j] = __fadd_rn(r[j], __fmul_rn(d, d));
    }
  return __fadd_rn(__fadd_rn(__fadd_rn(r[0], r[1]), __fadd_rn(r[2], r[3])),
                   __fadd_rn(__fadd_rn(r[4], r[5]), __fadd_rn(r[6], r[7])));
}

// ---------------- K1: sim + top5 + softmax + x_enh (unchanged from r15) ----------------
// 512 blocks x 256 thr; 64 tokens/block; chunk = 64 mem rows (16 chunks).
extern __shared__ float4 lds4[];  // 8192 float4 = 128 KB (dynamic)
__global__ __launch_bounds__(256, 1) void k_enh(const float* __restrict__ x,
                                                const float* __restrict__ mem,
                                                float* __restrict__ xenh) {
  float4* xt = lds4;          // 64 rows x 64 f4 (64 KB), swizzled
  float4* mt = lds4 + 4096;   // 64 rows x 64 f4 (64 KB), swizzled
  float* cv = (float*)lds4;             // [64][80]
  int*   ck = (int*)lds4 + 5120;        // [64][80]
  float* av = (float*)lds4 + 10240;     // [64][5]
  int*   ak = (int*)lds4 + 10560;       // [64][5]

  const int tid = threadIdx.x;
  const int tg = tid >> 4;
  const int kg = tid & 15;
  const int tokenBase = blockIdx.x * 64;

  {
    const float4* xg = (const float4*)(x + (size_t)tokenBase * 256);
    const float4* mg = (const float4*)mem;
#pragma unroll
    for (int i = 0; i < 16; ++i) {
      const int p = tid + 256 * i;
      const int row = p >> 6, q = p & 63;
      xt[row * 64 + SWZ(row, q)] = xg[p];
      mt[row * 64 + SWZ(row, q)] = mg[p];
    }
  }
  __syncthreads();

  float t5v[4][5]; int t5k[4][5];
#pragma unroll
  for (int i = 0; i < 4; ++i)
#pragma unroll
    for (int r = 0; r < 5; ++r) { t5v[i][r] = -INFINITY; t5k[i][r] = 0; }

  for (int kc = 0; kc < 16; ++kc) {
    float4 st[16];
    if (kc < 15) {
      const float4* mg = (const float4*)mem + (size_t)(kc + 1) * 4096;
#pragma unroll
      for (int i = 0; i < 16; ++i) st[i] = mg[tid + 256 * i];
    }

    float4 acc[4][4];
#pragma unroll
    for (int i = 0; i < 4; ++i)
#pragma unroll
      for (int j = 0; j < 4; ++j) acc[i][j] = make_float4(0.f, 0.f, 0.f, 0.f);

#pragma unroll 4
    for (int q = 0; q < 64; ++q) {
      float4 mv[4], xv[4];
#pragma unroll
      for (int j = 0; j < 4; ++j) {
        const int row = 4 * kg + j;
        mv[j] = mt[row * 64 + SWZ(row, q)];
      }
#pragma unroll
      for (int i = 0; i < 4; ++i) {
        const int row = 4 * tg + i;
        xv[i] = xt[row * 64 + SWZ(row, q)];
      }
#pragma unroll
      for (int i = 0; i < 4; ++i)
#pragma unroll
        for (int j = 0; j < 4; ++j) {
          acc[i][j].x = __fadd_rn(acc[i][j].x, __fmul_rn(xv[i].x, mv[j].x));
          acc[i][j].y = __fadd_rn(acc[i][j].y, __fmul_rn(xv[i].y, mv[j].y));
          acc[i][j].z = __fadd_rn(acc[i][j].z, __fmul_rn(xv[i].z, mv[j].z));
          acc[i][j].w = __fadd_rn(acc[i][j].w, __fmul_rn(xv[i].w, mv[j].w));
        }
    }

#pragma unroll
    for (int i = 0; i < 4; ++i)
#pragma unroll
      for (int j = 0; j < 4; ++j) {
        const float v = __fadd_rn(__fadd_rn(acc[i][j].x, acc[i][j].z),
                                  __fadd_rn(acc[i][j].y, acc[i][j].w));
        const int kk = kc * 64 + 4 * kg + j;
        if (v > t5v[i][4]) {
          t5v[i][4] = v; t5k[i][4] = kk;
          if (t5v[i][4] > t5v[i][3]) { float a = t5v[i][3]; t5v[i][3] = t5v[i][4]; t5v[i][4] = a; int ia = t5k[i][3]; t5k[i][3] = t5k[i][4]; t5k[i][4] = ia; }
          if (t5v[i][3] > t5v[i][2]) { float a = t5v[i][2]; t5v[i][2] = t5v[i][3]; t5v[i][3] = a; int ia = t5k[i][2]; t5k[i][2] = t5k[i][3]; t5k[i][3] = ia; }
          if (t5v[i][2] > t5v[i][1]) { float a = t5v[i][1]; t5v[i][1] = t5v[i][2]; t5v[i][2] = a; int ia = t5k[i][1]; t5k[i][1] = t5k[i][2]; t5k[i][2] = ia; }
          if (t5v[i][1] > t5v[i][0]) { float a = t5v[i][0]; t5v[i][0] = t5v[i][1]; t5v[i][1] = a; int ia = t5k[i][0]; t5k[i][0] = t5k[i][1]; t5k[i][1] = ia; }
        }
      }

    __syncthreads();
    if (kc < 15) {
#pragma unroll
      for (int i = 0; i < 16; ++i) {
        const int p = tid + 256 * i;
        const int row = p >> 6, q = p & 63;
        mt[row * 64 + SWZ(row, q)] = st[i];
      }
      __syncthreads();
    }
  }
  __syncthreads();

#pragma unroll
  for (int i = 0; i < 4; ++i) {
    const int token = 4 * tg + i;
#pragma unroll
    for (int r = 0; r < 5; ++r) {
      cv[token * 80 + kg * 5 + r] = t5v[i][r];
      ck[token * 80 + kg * 5 + r] = t5k[i][r];
    }
  }
  __syncthreads();

  if (tid < 64) {
    const int token = tid;
    float tv[5]; int tk[5];
#pragma unroll
    for (int r = 0; r < 5; ++r) {
      float best = -INFINITY; int bi = 0, bk = 0x7fffffff;
      for (int c = 0; c < 80; ++c) {
        const float vv = cv[token * 80 + c]; const int kkc = ck[token * 80 + c];
        if (vv > best || (vv == best && kkc < bk)) { best = vv; bi = c; bk = kkc; }
      }
      tv[r] = best; tk[r] = bk; cv[token * 80 + bi] = -INFINITY;
    }
    float mx = tv[0];
#pragma unroll
    for (int r = 1; r < 5; ++r) mx = fmaxf(mx, tv[r]);
    float e[5];
#pragma unroll
    for (int r = 0; r < 5; ++r)
      e[r] = (float)exp((double)__fsub_rn(tv[r], mx));
    float s = e[0];
#pragma unroll
    for (int r = 1; r < 5; ++r) s = __fadd_rn(s, e[r]);
#pragma unroll
    for (int r = 0; r < 5; ++r) { av[token * 5 + r] = __fdiv_rn(e[r], s); ak[token * 5 + r] = tk[r]; }
  }
  __syncthreads();

#pragma unroll
  for (int i = 0; i < 16; ++i) {
    const int flat = tid + 256 * i;
    const int token = flat >> 6, q = flat & 63;
    const float a0 = av[token * 5 + 0], a1 = av[token * 5 + 1], a2 = av[token * 5 + 2],
                a3 = av[token * 5 + 3], a4 = av[token * 5 + 4];
    const float4 xv = ((const float4*)(x + (size_t)(tokenBase + token) * 256))[q];
    const float4 m0 = ((const float4*)(mem + (size_t)ak[token * 5 + 0] * 256))[q];
    const float4 m1 = ((const float4*)(mem + (size_t)ak[token * 5 + 1] * 256))[q];
    const float4 m2 = ((const float4*)(mem + (size_t)ak[token * 5 + 2] * 256))[q];
    const float4 m3 = ((const float4*)(mem + (size_t)ak[token * 5 + 3] * 256))[q];
    const float4 m4 = ((const float4*)(mem + (size_t)ak[token * 5 + 4] * 256))[q];
    float4 o;
    {
      float ctx = __fmul_rn(a0, m0.x);
      ctx = __fadd_rn(ctx, __fmul_rn(a1, m1.x));
      ctx = __fadd_rn(ctx, __fmul_rn(a2, m2.x));
      ctx = __fadd_rn(ctx, __fmul_rn(a3, m3.x));
      ctx = __fadd_rn(ctx, __fmul_rn(a4, m4.x));
      o.x = __fadd_rn(xv.x, ctx);
    }
    {
      float ctx = __fmul_rn(a0, m0.y);
      ctx = __fadd_rn(ctx, __fmul_rn(a1, m1.y));
      ctx = __fadd_rn(ctx, __fmul_rn(a2, m2.y));
      ctx = __fadd_rn(ctx, __fmul_rn(a3, m3.y));
      ctx = __fadd_rn(ctx, __fmul_rn(a4, m4.y));
      o.y = __fadd_rn(xv.y, ctx);
    }
    {
      float ctx = __fmul_rn(a0, m0.z);
      ctx = __fadd_rn(ctx, __fmul_rn(a1, m1.z));
      ctx = __fadd_rn(ctx, __fmul_rn(a2, m2.z));
      ctx = __fadd_rn(ctx, __fmul_rn(a3, m3.z));
      ctx = __fadd_rn(ctx, __fmul_rn(a4, m4.z));
      o.z = __fadd_rn(xv.z, ctx);
    }
    {
      float ctx = __fmul_rn(a0, m0.w);
      ctx = __fadd_rn(ctx, __fmul_rn(a1, m1.w));
      ctx = __fadd_rn(ctx, __fmul_rn(a2, m2.w));
      ctx = __fadd_rn(ctx, __fmul_rn(a3, m3.w));
      ctx = __fadd_rn(ctx, __fmul_rn(a4, m4.w));
      o.w = __fadd_rn(xv.w, ctx);
    }
    ((float4*)(xenh + (size_t)tokenBase * 256))[flat] = o;
  }
}

// ---------------- zero the per-iteration count buffers ----------------
__global__ __launch_bounds__(256) void k_zero(int* __restrict__ p, int n) {
  const int i = blockIdx.x * 256 + threadIdx.x;
  if (i < n) p[i] = 0;
}

// ---------------- K3: init centroids (bit copy of x_enh rows) ----------------
__global__ __launch_bounds__(64) void k_init(const float* __restrict__ xenh,
                                             const int* __restrict__ init_idx,
                                             float* __restrict__ cent) {
  const int i = blockIdx.x;  // b*10 + j
  const int b = i / NC;
  const int s = init_idx[i];
  const int l = threadIdx.x;
  ((float4*)(cent + (size_t)i * 256))[l] =
      ((const float4*)(xenh + ((size_t)b * 4096 + s) * 256))[l];
}

// ---------------- K5: assignment -- all lanes, 2 lanes per token ----------------
// 256 blocks x 256 thr; 128 tokens/block. Lane pair (2i, 2i+1) = token, halves
// h=0/1 compute independent 128-block folds (exact r10 per-block order); the
// combine fadd(blk0, blk1) is commutative -> both lanes get identical dist bits
// -> identical argmin. Even lane writes.
__global__ __launch_bounds__(256) void k_assign(const float* __restrict__ xenh,
                                                const float* __restrict__ cent,
                                                int* __restrict__ assign,
                                                int* __restrict__ cnt) {
  __shared__ float cl[NC * 256];  // 10 KB
  const int tid = threadIdx.x;
  const int tokenBase = blockIdx.x * 128;
  const int b = blockIdx.x >> 5;    // 32 blocks per batch
  for (int i = tid; i < NC * 256; i += 256)
    cl[i] = cent[(size_t)b * NC * 256 + i];
  __syncthreads();

  const int token = tokenBase + (tid >> 1);
  const int h = tid & 1;
  const float* px = xenh + (size_t)token * 256 + h * 128;

  float best = INFINITY; int bk = 0;
#pragma unroll
  for (int k = 0; k < NC; ++k) {
    const float blkOwn = sumsqdiff128_np(px, cl + k * 256 + h * 128);
    const float blkOther = __shfl_xor(blkOwn, 1);
    // dist = fadd(blk0, blk1); commutative -> same bits on both lanes
    const float dist = __fadd_rn(blkOwn, blkOther);
    if (dist < best) { best = dist; bk = k; }
  }
  if (h == 0) assign[token] = bk;
#pragma unroll
  for (int k = 0; k < NC; ++k) {
    const unsigned long long m =
        __ballot(bk == k) & 0x5555555555555555ULL;  // even lanes only
    if ((tid & 63) == 0) atomicAdd(&cnt[b * NC + k], (int)__popcll(m));
  }
}

// ---------------- K6: cluster sums -- r13 proven version (block per b,k,d-half) ----------------
// Per-(k,d) chain is strictly s-ascending with (a==k)?xe:+0.0 adds == r10 order.
__global__ __launch_bounds__(128) void k_sums(const float* __restrict__ xenh,
                                              const int* __restrict__ assign,
                                              const int* __restrict__ cnt,
                                              float* __restrict__ cent) {
  const int bid = blockIdx.x;        // 160 = 8b * 10k * 2 halves
  const int b = bid / 20;
  const int rem = bid % 20;
  const int k = rem >> 1;
  const int d = (rem & 1) * 128 + threadIdx.x;
  const float* xb = xenh + (size_t)b * 4096 * 256 + d;
  const int* ab = assign + b * 4096;
  float acc = 0.0f;
#pragma unroll 8
  for (int s = 0; s < 4096; ++s) {
    const float xe = xb[(size_t)s * 256];
    const int a = ab[s];
    acc = __fadd_rn(acc, (a == k) ? xe : 0.0f);
  }
  const int c = cnt[b * NC + k];
  cent[((size_t)(b * NC + k)) * 256 + d] = (c == 0) ? 0.0f : __fdiv_rn(acc, (float)c);
}

// ---------------- K7: quantize ----------------
__global__ __launch_bounds__(256) void k_quant(const float* __restrict__ cent,
                                               const int* __restrict__ assign,
                                               float* __restrict__ out) {
  const int token = blockIdx.x * 4 + (threadIdx.x >> 6);
  const int l = threadIdx.x & 63;
  const int b = token >> 12;
  const int a = assign[token];
  ((float4*)out)[(size_t)token * 64 + l] =
      ((const float4*)cent)[(size_t)(b * NC + a) * 64 + l];
}

extern "C" void kernel_launch(void* const* d_in, const int* in_sizes, int n_in,
                              void* d_out, int out_size, void* d_ws, size_t ws_size,
                              hipStream_t stream) {
  const float* x = (const float*)d_in[0];      // [8,4096,256] f32
  const float* mem = (const float*)d_in[1];    // [1024,256] f32
  const int* init_idx = (const int*)d_in[2];   // [8,10] i32
  float* xenh = (float*)d_out;                 // x_enh materialized in d_out
  char* ws = (char*)d_ws;

  float* cent   = (float*)(ws);                //  81920 B
  int*   assign = (int*)  (ws + 81920);        // 131072 B
  int*   cntbuf = (int*)  (ws + 212992);       // KITERS*8*NC ints

  (void)hipFuncSetAttribute((const void*)k_enh,
                            hipFuncAttributeMaxDynamicSharedMemorySize, 131072);

  k_zero<<<4, 256, 0, stream>>>(cntbuf, KITERS * 8 * NC);
  k_enh<<<512, 256, 131072, stream>>>(x, mem, xenh);
  k_init<<<80, 64, 0, stream>>>(xenh, init_idx, cent);
  for (int it = 0; it < KITERS; ++it) {
    k_assign<<<256, 256, 0, stream>>>(xenh, cent, assign, cntbuf + it * 8 * NC);
    k_sums<<<160, 128, 0, stream>>>(xenh, assign, cntbuf + it * 8 * NC, cent);
  }
  k_quant<<<8192, 256, 0, stream>>>(cent, assign, (float*)d_out);
}